// Round 5
// baseline (140.212 us; speedup 1.0000x reference)
//
#include <hip/hip_runtime.h>
#include <hip/hip_bf16.h>

#define BB   8
#define SCTX 4096
#define SQ   512
#define EE   300
#define HH   128
#define EP   320    // E padded to multiple of 32
#define CST  328    // staged fp32->bf16 E-row stride (shorts)
#define QCH  136    // chunk row stride (shorts) = 272 B = 17x16 B: EVERY row 16-B aligned.
                    // (264-B stride misaligns odd rows -> HW-split ds_b128, 2x LDS cost.)
#define LOG2E 1.4426950408889634f

// HIP predefines short4/float4/uint4 (hip_vector_types.h) — never shadow them.
typedef short bhalf4 __attribute__((ext_vector_type(4)));
typedef short short8 __attribute__((ext_vector_type(8)));
typedef float f32x4  __attribute__((ext_vector_type(4)));
typedef unsigned u32x4 __attribute__((ext_vector_type(4)));

#define MFMA16(a, b, c) __builtin_amdgcn_mfma_f32_16x16x32_bf16((a), (b), (c), 0, 0, 0)

__device__ __forceinline__ short f2bf(float f) {
  unsigned u = __builtin_bit_cast(unsigned, f);
  u += 0x7fffu + ((u >> 16) & 1u);
  return (short)(u >> 16);
}
__device__ __forceinline__ float bf2f(short s) {
  return __builtin_bit_cast(float, ((unsigned)(unsigned short)s) << 16);
}
__device__ __forceinline__ unsigned pack2(float a, float b) {
  return (unsigned)(unsigned short)f2bf(a) | ((unsigned)(unsigned short)f2bf(b) << 16);
}

// ---------------- kernel 0: W (fp32 [128][300]) -> bf16 fragment-swizzled wsw ---------
__global__ void k_wpad(const float* __restrict__ W, short* __restrict__ wsw) {
  const int h = blockIdx.x, k = threadIdx.x;
  float v = (k < EE) ? W[h * EE + k] : 0.0f;
  const int m = h >> 4, t = h & 15, kk = k >> 5, quad = (k >> 3) & 3, j = k & 7;
  wsw[((kk * 8 + m) * 64 + quad * 16 + t) * 8 + j] = f2bf(v);
}

// ---------------- kernel 1: qst logits = relu(qst @ W^T + b) -> ql [b][q][h], qlT [b][h][q]
__global__ __launch_bounds__(256) void k_qlog(const float* __restrict__ qst,
                                              const short* __restrict__ wsw,
                                              const float* __restrict__ bias,
                                              short* __restrict__ ql,
                                              short* __restrict__ qlT) {
  const int b = blockIdx.y;
  const int m0 = blockIdx.x * 32;
  const int tid = threadIdx.x;
  const int w = tid >> 6, l = tid & 63, t = l & 15, quad = l >> 4;
  const int g = w >> 1, hf = w & 1;

  __shared__ __align__(16) short cst[32 * CST];

  const float4* cbase = (const float4*)(qst + (size_t)(b * SQ + m0) * EE);
#pragma unroll
  for (int j = 0; j < 10; ++j) {
    int i4 = tid + j * 256;
    if (i4 < 2400) {
      float4 v = cbase[i4];
      int row = i4 / 75, c4 = i4 - row * 75;
      short* dp = cst + row * CST + c4 * 4;
      dp[0] = f2bf(v.x); dp[1] = f2bf(v.y); dp[2] = f2bf(v.z); dp[3] = f2bf(v.w);
    }
  }
  for (int i = tid; i < 320; i += 256) {
    int row = i / 10, c = (i - row * 10) * 2;
    cst[row * CST + 300 + c] = 0;
    cst[row * CST + 301 + c] = 0;
  }
  __syncthreads();

  const short* arow = cst + (g * 16 + t) * CST;
  f32x4 acc[4] = {};
#pragma unroll
  for (int kk = 0; kk < 10; ++kk) {
    const int k = kk * 32 + quad * 8;
    short8 a = *(const short8*)(arow + k);
#pragma unroll
    for (int n = 0; n < 4; ++n) {
      short8 w8 = *(const short8*)(wsw + ((kk * 8 + hf * 4 + n) * 64 + l) * 8);
      acc[n] = MFMA16(a, w8, acc[n]);
    }
  }
#pragma unroll
  for (int n = 0; n < 4; ++n) {
    const int h = (hf * 4 + n) * 16 + t;
    const float bv = bias[h];
#pragma unroll
    for (int r = 0; r < 4; ++r) {
      float v = fmaxf(acc[n][r] + bv, 0.0f);
      short s16 = f2bf(v);
      const int row = m0 + g * 16 + quad * 4 + r;
      ql[((size_t)b * SQ + row) * HH + h] = s16;
      qlT[((size_t)b * HH + h) * SQ + row] = s16;
    }
  }
}

// ---------------- kernel 2: fused ctx-logits + QK^T + softmax (no-max) + PV ------------
// grid (SCTX/64, B), block 256 = 4 waves; wave w owns ctx rows m0+w*16..+15, full q=512.
//
// R11: B-operands from global = latency collapse (MfmaUtil 5.4%). DON'T.
// R14: ds_read_b64_tr_b16 V-derivation = wrong element order, absmax 2.27. DON'T retry blind.
// R15 (this): swapped-S + register-P + merged staging.
//  * S computed as MFMA16(b8, af) (operand swap, same registers): C-layout gives lane
//    (t,quad) reg r = S[ctx = t][q = n2*16 + quad*4 + r] -> P for the lane's OWN ctx row.
//  * P packed to bf16 in-register; PV A-fragments assembled with 8 __shfl + 4 selects
//    per kk (dest lane (t,quad) j<-src lane (t,(quad&1)*2+(j>>2)), n2=kk*2+(quad>>1),
//    r=j&3). pbw LDS round-trip (128 scalar writes + 16 b128 reads/thread) DELETED.
//  * Freed pbw -> QL(c) and V(c) both resident (2x34,816B): chunk loop is
//    [sync; issue c+1 loads; S+PV; sync; write c+1] = 2 barriers/chunk (was 4).
//  * rsum: lane accumulates over its q's; reduce shfl_xor 16,32 (over quads), then
//    rinv[r] = 1/shfl(rtot, quad*4+r) for the o-rows.
// Max-subtraction dropped (S_max ~16 << 88; -8 centering in maskh; R10-verified).
// __launch_bounds__ min-waves MUST stay 2 (3 => 84-VGPR spill binary, R6/R8).
__global__ __launch_bounds__(256, 2) void k_attn(const float* __restrict__ ctx,
                                                 const short* __restrict__ wsw,
                                                 const float* __restrict__ bias,
                                                 const int* __restrict__ mask,
                                                 const short* __restrict__ ql,
                                                 const short* __restrict__ qlT,
                                                 float* __restrict__ out) {
  const int b = blockIdx.y;
  const int m0 = blockIdx.x * 64;
  const int tid = threadIdx.x;
  const int w = tid >> 6, l = tid & 63, t = l & 15, quad = l >> 4;
  const int g = w >> 1, hf = w & 1;

  __shared__ __align__(16) short uq[17408];  // cst [32][328] -> QL chunk [128 q][136]
  __shared__ __align__(16) short uv[17408];  // clt [64][136] -> V chunk [128 h][136]
  __shared__ short maskh[SQ];                // bf16 mask+exp-centering offsets
  short* cst = uq;
  short* qch = uq;
  short* clt = uv;
  short* vch = uv;

  const short8* qsrc = (const short8*)(ql + (size_t)b * SQ * HH);
  const short8* vsrc = (const short8*)(qlT + (size_t)b * HH * SQ);

  // prologue: issue chunk-0 QL+V loads; latency hides under phase A.
  short8 qreg[8], vreg[8];
#pragma unroll
  for (int j = 0; j < 8; ++j) {
    int i = tid + j * 256;
    qreg[j] = qsrc[i];
    vreg[j] = vsrc[(i >> 4) * 64 + (i & 15)];  // qlT[h=i>>4][q-group i&15 of chunk 0]
  }

  for (int i = tid; i < SQ; i += 256)
    maskh[i] = f2bf(mask[b * SQ + i] ? -8.0f : -1e30f);  // -8 = exp-centering offset

  // ---- phase A: ctx_logits tile [64][128], two 32-row halves ----
  for (int i = 0; i < 2; ++i) {
    const float4* cbase = (const float4*)(ctx + ((size_t)b * SCTX + m0 + i * 32) * EE);
#pragma unroll
    for (int j = 0; j < 10; ++j) {
      int i4 = tid + j * 256;
      if (i4 < 2400) {
        float4 v = cbase[i4];
        int row = i4 / 75, c4 = i4 - row * 75;
        short* dp = cst + row * CST + c4 * 4;
        dp[0] = f2bf(v.x); dp[1] = f2bf(v.y); dp[2] = f2bf(v.z); dp[3] = f2bf(v.w);
      }
    }
    for (int k = tid; k < 320; k += 256) {
      int row = k / 10, c = (k - row * 10) * 2;
      cst[row * CST + 300 + c] = 0;
      cst[row * CST + 301 + c] = 0;
    }
    __syncthreads();
    const short* arow = cst + (g * 16 + t) * CST;
    f32x4 acc[4] = {};
#pragma unroll
    for (int kk = 0; kk < 10; ++kk) {
      const int k = kk * 32 + quad * 8;
      short8 a = *(const short8*)(arow + k);
#pragma unroll
      for (int n = 0; n < 4; ++n) {
        short8 w8 = *(const short8*)(wsw + ((kk * 8 + hf * 4 + n) * 64 + l) * 8);
        acc[n] = MFMA16(a, w8, acc[n]);
      }
    }
#pragma unroll
    for (int n = 0; n < 4; ++n) {
      const int h = (hf * 4 + n) * 16 + t;
      const float bv = bias[h];
#pragma unroll
      for (int r = 0; r < 4; ++r) {
        float v = fmaxf(acc[n][r] + bv, 0.0f);
        clt[(i * 32 + g * 16 + quad * 4 + r) * 136 + h] = f2bf(v);
      }
    }
    __syncthreads();  // clt written; cst free
  }

  // A-fragments for this wave's 16 ctx rows
  short8 af[4];
#pragma unroll
  for (int kk = 0; kk < 4; ++kk)
    af[kk] = *(const short8*)&clt[(w * 16 + t) * 136 + kk * 32 + quad * 8];
  __syncthreads();  // af reads drained before qch/vch overwrite uq/uv

  // pre-loop: write chunk 0 into both buffers
#pragma unroll
  for (int j = 0; j < 8; ++j) {
    int i = tid + j * 256;
    *(short8*)&qch[(i >> 4) * QCH + (i & 15) * 8] = qreg[j];
    *(short8*)&vch[(i >> 4) * QCH + (i & 15) * 8] = vreg[j];
  }

  const int srcA = ((quad & 1) * 2) * 16 + t;  // shfl source lanes for P-assembly
  const int srcB = srcA + 16;
  const bool hiq = quad >= 2;                  // dest-quad half selects n2 parity

  f32x4 o[8] = {};
  float rtot = 0.0f;
  for (int c = 0; c < 4; ++c) {
    __syncthreads();  // staged QL(c)/V(c) visible; prior writers synced
    if (c < 3) {      // issue next chunk's loads; consumed only after next barrier
#pragma unroll
      for (int j = 0; j < 8; ++j) {
        int i = tid + j * 256;
        qreg[j] = qsrc[(c + 1) * 2048 + i];
        vreg[j] = vsrc[(i >> 4) * 64 + (c + 1) * 16 + (i & 15)];
      }
    }
#pragma unroll
    for (int kk = 0; kk < 4; ++kk) {
      // --- S for n2 = kk*2 (even) and kk*2+1 (odd), operand-swapped ---
      f32x4 svE = {0.f, 0.f, 0.f, 0.f}, svO = {0.f, 0.f, 0.f, 0.f};
      const short* qrE = qch + ((kk * 2) * 16 + t) * QCH;
      const short* qrO = qch + ((kk * 2 + 1) * 16 + t) * QCH;
#pragma unroll
      for (int kx = 0; kx < 4; ++kx) {
        short8 b8e = *(const short8*)(qrE + kx * 32 + quad * 8);
        short8 b8o = *(const short8*)(qrO + kx * 32 + quad * 8);
        svE = MFMA16(b8e, af[kx], svE);   // swapped: A=QL-frag, B=ctx-frag
        svO = MFMA16(b8o, af[kx], svO);
      }
      // mask + exp; lane (t,quad) reg r = P[q = n2*16 + quad*4 + r][ctx = t]
      bhalf4 mbE = *(const bhalf4*)&maskh[c * 128 + (kk * 2) * 16 + quad * 4];
      bhalf4 mbO = *(const bhalf4*)&maskh[c * 128 + (kk * 2 + 1) * 16 + quad * 4];
      float pE[4], pO[4];
#pragma unroll
      for (int r = 0; r < 4; ++r) {
        pE[r] = exp2f((svE[r] + bf2f(mbE[r])) * LOG2E);
        pO[r] = exp2f((svO[r] + bf2f(mbO[r])) * LOG2E);
        rtot += pE[r] + pO[r];
      }
      unsigned pkE0 = pack2(pE[0], pE[1]), pkE1 = pack2(pE[2], pE[3]);
      unsigned pkO0 = pack2(pO[0], pO[1]), pkO1 = pack2(pO[2], pO[3]);
      // --- assemble PV A-fragment via quad-shuffles ---
      unsigned sE0 = (unsigned)__shfl((int)pkE0, srcA), sE1 = (unsigned)__shfl((int)pkE1, srcA);
      unsigned sO0 = (unsigned)__shfl((int)pkO0, srcA), sO1 = (unsigned)__shfl((int)pkO1, srcA);
      unsigned tE0 = (unsigned)__shfl((int)pkE0, srcB), tE1 = (unsigned)__shfl((int)pkE1, srcB);
      unsigned tO0 = (unsigned)__shfl((int)pkO0, srcB), tO1 = (unsigned)__shfl((int)pkO1, srcB);
      u32x4 av;
      av[0] = hiq ? sO0 : sE0;  // j=0,1  (src quad (quad&1)*2,   r0,r1)
      av[1] = hiq ? sO1 : sE1;  // j=2,3  (          ..           r2,r3)
      av[2] = hiq ? tO0 : tE0;  // j=4,5  (src quad (quad&1)*2+1, r0,r1)
      av[3] = hiq ? tO1 : tE1;  // j=6,7
      short8 pa = __builtin_bit_cast(short8, av);
      // --- PV for this kk (q-block kk*32..+31) ---
#pragma unroll
      for (int n = 0; n < 8; ++n) {
        short8 v8 = *(const short8*)&vch[(n * 16 + t) * QCH + kk * 32 + quad * 8];
        o[n] = MFMA16(pa, v8, o[n]);
      }
    }
    __syncthreads();  // all compute reads of qch/vch drained
    if (c < 3) {      // write next chunk (loads issued a full compute-phase ago)
#pragma unroll
      for (int j = 0; j < 8; ++j) {
        int i = tid + j * 256;
        *(short8*)&qch[(i >> 4) * QCH + (i & 15) * 8] = qreg[j];
        *(short8*)&vch[(i >> 4) * QCH + (i & 15) * 8] = vreg[j];
      }
    }
  }

  // ---- epilogue ----
  rtot += __shfl_xor(rtot, 16);
  rtot += __shfl_xor(rtot, 32);  // now lane x holds full denom for ctx row (x&15)
  f32x4 rinv;
#pragma unroll
  for (int r = 0; r < 4; ++r) rinv[r] = 1.0f / __shfl(rtot, quad * 4 + r);
  float* obase = out + ((size_t)b * SCTX + m0 + w * 16) * HH;
#pragma unroll
  for (int n = 0; n < 8; ++n)
#pragma unroll
    for (int r = 0; r < 4; ++r)
      obase[(quad * 4 + r) * HH + n * 16 + t] = o[n][r] * rinv[r];
}

extern "C" void kernel_launch(void* const* d_in, const int* in_sizes, int n_in,
                              void* d_out, int out_size, void* d_ws, size_t ws_size,
                              hipStream_t stream) {
  const float* ctx  = (const float*)d_in[0];
  const float* qst  = (const float*)d_in[1];
  const int*   mask = (const int*)d_in[2];
  const float* W    = (const float*)d_in[3];
  const float* bias = (const float*)d_in[4];
  float* out = (float*)d_out;

  // ws: wsw 80 KiB | ql 1 MiB | qlT 1 MiB
  short* wsw  = (short*)d_ws;
  short* ql   = (short*)((char*)d_ws + 81920);
  short* qlT  = ql + (size_t)BB * SQ * HH;

  k_wpad<<<dim3(HH), dim3(EP), 0, stream>>>(W, wsw);
  k_qlog<<<dim3(SQ / 32, BB), dim3(256), 0, stream>>>(qst, wsw, bias, ql, qlT);
  k_attn<<<dim3(SCTX / 64, BB), dim3(256), 0, stream>>>(ctx, wsw, bias, mask, ql, qlT, out);
}

// Round 6
// 121.958 us; speedup vs baseline: 1.1497x; 1.1497x over previous
//
#include <hip/hip_runtime.h>
#include <hip/hip_bf16.h>

#define BB   8
#define SCTX 4096
#define SQ   512
#define EE   300
#define HH   128
#define EP   320    // E padded to multiple of 32
#define CST  328    // staged fp32->bf16 E-row stride (shorts)
#define LOG2E 1.4426950408889634f

// HIP predefines short4/float4/uint4 (hip_vector_types.h) — never shadow them.
typedef short bhalf4 __attribute__((ext_vector_type(4)));
typedef short short8 __attribute__((ext_vector_type(8)));
typedef float f32x4  __attribute__((ext_vector_type(4)));
typedef unsigned u32x4 __attribute__((ext_vector_type(4)));

#define MFMA16(a, b, c) __builtin_amdgcn_mfma_f32_16x16x32_bf16((a), (b), (c), 0, 0, 0)

__device__ __forceinline__ short f2bf(float f) {
  unsigned u = __builtin_bit_cast(unsigned, f);
  u += 0x7fffu + ((u >> 16) & 1u);
  return (short)(u >> 16);
}
__device__ __forceinline__ float bf2f(short s) {
  return __builtin_bit_cast(float, ((unsigned)(unsigned short)s) << 16);
}
__device__ __forceinline__ unsigned pack2(float a, float b) {
  return (unsigned)(unsigned short)f2bf(a) | ((unsigned)(unsigned short)f2bf(b) << 16);
}
// global -> LDS direct DMA, 16 B per lane. LDS dest = wave-uniform base + lane*16
// (m104); global source is per-lane (pre-swizzle goes on the SOURCE, rule #21).
__device__ __forceinline__ void gload16(const void* g, void* lds) {
  __builtin_amdgcn_global_load_lds(
      (const __attribute__((address_space(1))) void*)g,
      (__attribute__((address_space(3))) void*)lds, 16, 0, 0);
}

// ---------------- kernel 0: W (fp32 [128][300]) -> bf16 fragment-swizzled wsw ---------
__global__ void k_wpad(const float* __restrict__ W, short* __restrict__ wsw) {
  const int h = blockIdx.x, k = threadIdx.x;
  float v = (k < EE) ? W[h * EE + k] : 0.0f;
  const int m = h >> 4, t = h & 15, kk = k >> 5, quad = (k >> 3) & 3, j = k & 7;
  wsw[((kk * 8 + m) * 64 + quad * 16 + t) * 8 + j] = f2bf(v);
}

// ---------------- kernel 1: qst logits = relu(qst @ W^T + b) -> ql [b][q][h], qlT [b][h][q]
__global__ __launch_bounds__(256) void k_qlog(const float* __restrict__ qst,
                                              const short* __restrict__ wsw,
                                              const float* __restrict__ bias,
                                              short* __restrict__ ql,
                                              short* __restrict__ qlT) {
  const int b = blockIdx.y;
  const int m0 = blockIdx.x * 32;
  const int tid = threadIdx.x;
  const int w = tid >> 6, l = tid & 63, t = l & 15, quad = l >> 4;
  const int g = w >> 1, hf = w & 1;

  __shared__ __align__(16) short cst[32 * CST];

  const float4* cbase = (const float4*)(qst + (size_t)(b * SQ + m0) * EE);
#pragma unroll
  for (int j = 0; j < 10; ++j) {
    int i4 = tid + j * 256;
    if (i4 < 2400) {
      float4 v = cbase[i4];
      int row = i4 / 75, c4 = i4 - row * 75;
      short* dp = cst + row * CST + c4 * 4;
      dp[0] = f2bf(v.x); dp[1] = f2bf(v.y); dp[2] = f2bf(v.z); dp[3] = f2bf(v.w);
    }
  }
  for (int i = tid; i < 320; i += 256) {
    int row = i / 10, c = (i - row * 10) * 2;
    cst[row * CST + 300 + c] = 0;
    cst[row * CST + 301 + c] = 0;
  }
  __syncthreads();

  const short* arow = cst + (g * 16 + t) * CST;
  f32x4 acc[4] = {};
#pragma unroll
  for (int kk = 0; kk < 10; ++kk) {
    const int k = kk * 32 + quad * 8;
    short8 a = *(const short8*)(arow + k);
#pragma unroll
    for (int n = 0; n < 4; ++n) {
      short8 w8 = *(const short8*)(wsw + ((kk * 8 + hf * 4 + n) * 64 + l) * 8);
      acc[n] = MFMA16(a, w8, acc[n]);
    }
  }
#pragma unroll
  for (int n = 0; n < 4; ++n) {
    const int h = (hf * 4 + n) * 16 + t;
    const float bv = bias[h];
#pragma unroll
    for (int r = 0; r < 4; ++r) {
      float v = fmaxf(acc[n][r] + bv, 0.0f);
      short s16 = f2bf(v);
      const int row = m0 + g * 16 + quad * 4 + r;
      ql[((size_t)b * SQ + row) * HH + h] = s16;
      qlT[((size_t)b * HH + h) * SQ + row] = s16;
    }
  }
}

// ---------------- kernel 2: fused ctx-logits + QK^T + softmax (no-max) + PV ------------
// grid (SCTX/64, B), block 256 = 4 waves; wave w owns ctx rows m0+w*16..+15, full q=512.
//
// R11: B-operands from global = latency collapse. DON'T.
// R14: tr_b16 V-derivation = wrong element order. DON'T retry blind.
// R15 POST-MORTEM: qreg/vreg register double-buffer (64 VGPRs live across compute)
//   spilled to scratch at the 128-VGPR allocation: WRITE_SIZE 16.4->40 MB, k_attn
//   43->57us. Register prefetch of full chunks does NOT fit this kernel. DON'T.
// R16 (this): keep R15's swapped-S + register-P compute (verified, absmax 0.0234375);
//   stage with __builtin_amdgcn_global_load_lds (zero staging VGPRs, zero ds_writes):
//  * qch [128 q][128 h], vch [128 h][128 q], unpadded, XOR-swizzled: LDS[row][cb]
//    holds global col-byte cb ^ ((row&7)<<4). DMA dest linear (base+lane*16);
//    the XOR is applied to each lane's GLOBAL source address (rule #21), and to
//    every LDS read (col-byte ^ ((row&7)<<4)). Same bank distribution as the
//    proven +8-short row padding (row-stride ≡ 4 dwords mod 32 ⇔ XOR by row&7).
//  * chunk loop: [stage-issue; sync (vmcnt drain); S+PV; sync] = 2 barriers/chunk.
//  * S operand-swapped MFMA16(b8, af): lane (t,quad) reg r = P[q=n2*16+quad*4+r][ctx=t];
//    P packed bf16 in-register, PV A-frags via 8 __shfl + 4 selects per kk.
// Max-subtraction dropped (S_max ~16 << 88; -8 centering in maskh; R10-verified).
// __launch_bounds__ min-waves MUST stay 2 (3 => 84-VGPR spill binary, R6/R8).
__global__ __launch_bounds__(256, 2) void k_attn(const float* __restrict__ ctx,
                                                 const short* __restrict__ wsw,
                                                 const float* __restrict__ bias,
                                                 const int* __restrict__ mask,
                                                 const short* __restrict__ ql,
                                                 const short* __restrict__ qlT,
                                                 float* __restrict__ out) {
  const int b = blockIdx.y;
  const int m0 = blockIdx.x * 64;
  const int tid = threadIdx.x;
  const int w = tid >> 6, l = tid & 63, t = l & 15, quad = l >> 4;
  const int g = w >> 1, hf = w & 1;

  __shared__ __align__(16) short uq[16384];  // cst [32][328] (20,992 B) -> qch [128][128]
  __shared__ __align__(16) short uv[16384];  // clt [64][136] (17,408 B) -> vch [128][128]
  __shared__ short maskh[SQ];                // bf16 mask+exp-centering offsets
  short* cst = uq;
  short* qch = uq;
  short* clt = uv;
  short* vch = uv;

  for (int i = tid; i < SQ; i += 256)
    maskh[i] = f2bf(mask[b * SQ + i] ? -8.0f : -1e30f);  // -8 = exp-centering offset

  // ---- phase A: ctx_logits tile [64][128], two 32-row halves ----
  for (int i = 0; i < 2; ++i) {
    const float4* cbase = (const float4*)(ctx + ((size_t)b * SCTX + m0 + i * 32) * EE);
#pragma unroll
    for (int j = 0; j < 10; ++j) {
      int i4 = tid + j * 256;
      if (i4 < 2400) {
        float4 v = cbase[i4];
        int row = i4 / 75, c4 = i4 - row * 75;
        short* dp = cst + row * CST + c4 * 4;
        dp[0] = f2bf(v.x); dp[1] = f2bf(v.y); dp[2] = f2bf(v.z); dp[3] = f2bf(v.w);
      }
    }
    for (int k = tid; k < 320; k += 256) {
      int row = k / 10, c = (k - row * 10) * 2;
      cst[row * CST + 300 + c] = 0;
      cst[row * CST + 301 + c] = 0;
    }
    __syncthreads();
    const short* arow = cst + (g * 16 + t) * CST;
    f32x4 acc[4] = {};
#pragma unroll
    for (int kk = 0; kk < 10; ++kk) {
      const int k = kk * 32 + quad * 8;
      short8 a = *(const short8*)(arow + k);
#pragma unroll
      for (int n = 0; n < 4; ++n) {
        short8 w8 = *(const short8*)(wsw + ((kk * 8 + hf * 4 + n) * 64 + l) * 8);
        acc[n] = MFMA16(a, w8, acc[n]);
      }
    }
#pragma unroll
    for (int n = 0; n < 4; ++n) {
      const int h = (hf * 4 + n) * 16 + t;
      const float bv = bias[h];
#pragma unroll
      for (int r = 0; r < 4; ++r) {
        float v = fmaxf(acc[n][r] + bv, 0.0f);
        clt[(i * 32 + g * 16 + quad * 4 + r) * 136 + h] = f2bf(v);
      }
    }
    __syncthreads();  // clt written; cst free
  }

  // A-fragments for this wave's 16 ctx rows
  short8 af[4];
#pragma unroll
  for (int kk = 0; kk < 4; ++kk)
    af[kk] = *(const short8*)&clt[(w * 16 + t) * 136 + kk * 32 + quad * 8];
  __syncthreads();  // af reads drained before DMA overwrites uq/uv

  const int srcA = ((quad & 1) * 2) * 16 + t;  // shfl source lanes for P-assembly
  const int srcB = srcA + 16;
  const bool hiq = quad >= 2;                  // dest-quad half selects n2 parity
  const int sx = (t & 7) << 3;                 // read-side XOR (shorts)
  const int rl = l >> 4;                       // DMA: lane's row-within-call
  const int cb = (l & 15) * 16;                // DMA: lane's linear dest col-byte

  f32x4 o[8] = {};
  float rtot = 0.0f;
  for (int c = 0; c < 4; ++c) {
    // ---- stage chunk c via DMA (prior reads drained by trailing/af barrier) ----
#pragma unroll
    for (int s = 0; s < 8; ++s) {
      const int row = w * 32 + s * 4 + rl;
      const int sw = cb ^ ((row & 7) << 4);  // pre-swizzled SOURCE col-byte
      gload16((const char*)(ql + ((size_t)b * SQ + c * 128 + row) * HH) + sw,
              qch + (w * 32 + s * 4) * 128);
      gload16((const char*)(qlT + ((size_t)b * HH + row) * SQ + c * 128) + sw,
              vch + (w * 32 + s * 4) * 128);
    }
    __syncthreads();  // vmcnt(0) drain -> staged chunk visible to all waves

#pragma unroll
    for (int kk = 0; kk < 4; ++kk) {
      // --- S for q-rows n2 = kk*2 (even) and kk*2+1 (odd), operand-swapped ---
      f32x4 svE = {0.f, 0.f, 0.f, 0.f}, svO = {0.f, 0.f, 0.f, 0.f};
      const short* qrE = qch + ((kk * 2) * 16 + t) * 128;
      const short* qrO = qrE + 16 * 128;
#pragma unroll
      for (int kx = 0; kx < 4; ++kx) {
        const int co = (kx * 32 + quad * 8) ^ sx;
        short8 b8e = *(const short8*)(qrE + co);
        short8 b8o = *(const short8*)(qrO + co);
        svE = MFMA16(b8e, af[kx], svE);   // swapped: A=QL-frag, B=ctx-frag
        svO = MFMA16(b8o, af[kx], svO);
      }
      // mask + exp; lane (t,quad) reg r = P[q = n2*16 + quad*4 + r][ctx = t]
      bhalf4 mbE = *(const bhalf4*)&maskh[c * 128 + (kk * 2) * 16 + quad * 4];
      bhalf4 mbO = *(const bhalf4*)&maskh[c * 128 + (kk * 2 + 1) * 16 + quad * 4];
      float pE[4], pO[4];
#pragma unroll
      for (int r = 0; r < 4; ++r) {
        pE[r] = exp2f((svE[r] + bf2f(mbE[r])) * LOG2E);
        pO[r] = exp2f((svO[r] + bf2f(mbO[r])) * LOG2E);
        rtot += pE[r] + pO[r];
      }
      unsigned pkE0 = pack2(pE[0], pE[1]), pkE1 = pack2(pE[2], pE[3]);
      unsigned pkO0 = pack2(pO[0], pO[1]), pkO1 = pack2(pO[2], pO[3]);
      // --- assemble PV A-fragment via quad-shuffles ---
      unsigned sE0 = (unsigned)__shfl((int)pkE0, srcA), sE1 = (unsigned)__shfl((int)pkE1, srcA);
      unsigned sO0 = (unsigned)__shfl((int)pkO0, srcA), sO1 = (unsigned)__shfl((int)pkO1, srcA);
      unsigned tE0 = (unsigned)__shfl((int)pkE0, srcB), tE1 = (unsigned)__shfl((int)pkE1, srcB);
      unsigned tO0 = (unsigned)__shfl((int)pkO0, srcB), tO1 = (unsigned)__shfl((int)pkO1, srcB);
      u32x4 av;
      av[0] = hiq ? sO0 : sE0;  // j=0,1  (src quad (quad&1)*2,   r0,r1)
      av[1] = hiq ? sO1 : sE1;  // j=2,3
      av[2] = hiq ? tO0 : tE0;  // j=4,5  (src quad (quad&1)*2+1, r0,r1)
      av[3] = hiq ? tO1 : tE1;  // j=6,7
      short8 pa = __builtin_bit_cast(short8, av);
      // --- PV for this kk (q-block kk*32..+31) ---
#pragma unroll
      for (int n = 0; n < 8; ++n) {
        const int co = (kk * 32 + quad * 8) ^ sx;
        short8 v8 = *(const short8*)&vch[(n * 16 + t) * 128 + co];
        o[n] = MFMA16(pa, v8, o[n]);
      }
    }
    __syncthreads();  // all compute reads drained before next chunk's DMA overwrite
  }

  // ---- epilogue ----
  rtot += __shfl_xor(rtot, 16);
  rtot += __shfl_xor(rtot, 32);  // lane x now holds full denom for ctx row (x&15)
  f32x4 rinv;
#pragma unroll
  for (int r = 0; r < 4; ++r) rinv[r] = 1.0f / __shfl(rtot, quad * 4 + r);
  float* obase = out + ((size_t)b * SCTX + m0 + w * 16) * HH;
#pragma unroll
  for (int n = 0; n < 8; ++n)
#pragma unroll
    for (int r = 0; r < 4; ++r)
      obase[(quad * 4 + r) * HH + n * 16 + t] = o[n][r] * rinv[r];
}

extern "C" void kernel_launch(void* const* d_in, const int* in_sizes, int n_in,
                              void* d_out, int out_size, void* d_ws, size_t ws_size,
                              hipStream_t stream) {
  const float* ctx  = (const float*)d_in[0];
  const float* qst  = (const float*)d_in[1];
  const int*   mask = (const int*)d_in[2];
  const float* W    = (const float*)d_in[3];
  const float* bias = (const float*)d_in[4];
  float* out = (float*)d_out;

  // ws: wsw 80 KiB | ql 1 MiB | qlT 1 MiB
  short* wsw  = (short*)d_ws;
  short* ql   = (short*)((char*)d_ws + 81920);
  short* qlT  = ql + (size_t)BB * SQ * HH;

  k_wpad<<<dim3(HH), dim3(EP), 0, stream>>>(W, wsw);
  k_qlog<<<dim3(SQ / 32, BB), dim3(256), 0, stream>>>(qst, wsw, bias, ql, qlT);
  k_attn<<<dim3(SCTX / 64, BB), dim3(256), 0, stream>>>(ctx, wsw, bias, mask, ql, qlT, out);
}

// Round 7
// 121.129 us; speedup vs baseline: 1.1575x; 1.0068x over previous
//
#include <hip/hip_runtime.h>
#include <hip/hip_bf16.h>

#define BB   8
#define SCTX 4096
#define SQ   512
#define EE   300
#define HH   128
#define EP   320    // E padded to multiple of 32
#define CST  328    // staged fp32->bf16 E-row stride (shorts)
#define LOG2E 1.4426950408889634f

// HIP predefines short4/float4/uint4 (hip_vector_types.h) — never shadow them.
typedef short bhalf4 __attribute__((ext_vector_type(4)));
typedef short short8 __attribute__((ext_vector_type(8)));
typedef float f32x4  __attribute__((ext_vector_type(4)));
typedef unsigned u32x4 __attribute__((ext_vector_type(4)));

#define MFMA16(a, b, c) __builtin_amdgcn_mfma_f32_16x16x32_bf16((a), (b), (c), 0, 0, 0)

__device__ __forceinline__ short f2bf(float f) {
  unsigned u = __builtin_bit_cast(unsigned, f);
  u += 0x7fffu + ((u >> 16) & 1u);
  return (short)(u >> 16);
}
__device__ __forceinline__ float bf2f(short s) {
  return __builtin_bit_cast(float, ((unsigned)(unsigned short)s) << 16);
}
__device__ __forceinline__ unsigned pack2(float a, float b) {
  return (unsigned)(unsigned short)f2bf(a) | ((unsigned)(unsigned short)f2bf(b) << 16);
}
// global -> LDS direct DMA, 16 B per lane. LDS dest = wave-uniform base + lane*16
// (m104); global source is per-lane (pre-swizzle goes on the SOURCE, rule #21).
__device__ __forceinline__ void gload16(const void* g, void* lds) {
  __builtin_amdgcn_global_load_lds(
      (const __attribute__((address_space(1))) void*)g,
      (__attribute__((address_space(3))) void*)lds, 16, 0, 0);
}

// ---------------- kernel 0: W (fp32 [128][300]) -> bf16 fragment-swizzled wsw ---------
__global__ void k_wpad(const float* __restrict__ W, short* __restrict__ wsw) {
  const int h = blockIdx.x, k = threadIdx.x;
  float v = (k < EE) ? W[h * EE + k] : 0.0f;
  const int m = h >> 4, t = h & 15, kk = k >> 5, quad = (k >> 3) & 3, j = k & 7;
  wsw[((kk * 8 + m) * 64 + quad * 16 + t) * 8 + j] = f2bf(v);
}

// ---------------- kernel 1: qst logits = relu(qst @ W^T + b) -> ql [b][q][h], qlT [b][h][q]
__global__ __launch_bounds__(256) void k_qlog(const float* __restrict__ qst,
                                              const short* __restrict__ wsw,
                                              const float* __restrict__ bias,
                                              short* __restrict__ ql,
                                              short* __restrict__ qlT) {
  const int b = blockIdx.y;
  const int m0 = blockIdx.x * 32;
  const int tid = threadIdx.x;
  const int w = tid >> 6, l = tid & 63, t = l & 15, quad = l >> 4;
  const int g = w >> 1, hf = w & 1;

  __shared__ __align__(16) short cst[32 * CST];

  const float4* cbase = (const float4*)(qst + (size_t)(b * SQ + m0) * EE);
#pragma unroll
  for (int j = 0; j < 10; ++j) {
    int i4 = tid + j * 256;
    if (i4 < 2400) {
      float4 v = cbase[i4];
      int row = i4 / 75, c4 = i4 - row * 75;
      bhalf4 s4; s4[0] = f2bf(v.x); s4[1] = f2bf(v.y); s4[2] = f2bf(v.z); s4[3] = f2bf(v.w);
      *(bhalf4*)(cst + row * CST + c4 * 4) = s4;   // byte = row*656 + c4*8, 8-B aligned
    }
  }
  for (int i = tid; i < 320; i += 256) {
    int row = i / 10, c = (i - row * 10) * 2;
    *(int*)&cst[row * CST + 300 + c] = 0;          // byte 4-aligned (c even)
  }
  __syncthreads();

  const short* arow = cst + (g * 16 + t) * CST;
  f32x4 acc[4] = {};
#pragma unroll
  for (int kk = 0; kk < 10; ++kk) {
    const int k = kk * 32 + quad * 8;
    short8 a = *(const short8*)(arow + k);
    short8 w8[4];
#pragma unroll
    for (int n = 0; n < 4; ++n)
      w8[n] = *(const short8*)(wsw + ((kk * 8 + hf * 4 + n) * 64 + l) * 8);
#pragma unroll
    for (int n = 0; n < 4; ++n) acc[n] = MFMA16(a, w8[n], acc[n]);
  }
#pragma unroll
  for (int n = 0; n < 4; ++n) {
    const int h = (hf * 4 + n) * 16 + t;
    const float bv = bias[h];
    bhalf4 s4;
#pragma unroll
    for (int r = 0; r < 4; ++r) {
      float v = fmaxf(acc[n][r] + bv, 0.0f);
      short s16 = f2bf(v);
      s4[r] = s16;
      const int row = m0 + g * 16 + quad * 4 + r;
      ql[((size_t)b * SQ + row) * HH + h] = s16;   // scatter (h fixed, row varies)
    }
    // qlT rows quad*4..+3 are CONTIGUOUS (stride 1 short): one b64 store (8-B aligned)
    *(bhalf4*)&qlT[((size_t)b * HH + h) * SQ + m0 + g * 16 + quad * 4] = s4;
  }
}

// ---------------- kernel 2: fused ctx-logits + QK^T + softmax (no-max) + PV ------------
// grid (SCTX/64, B), block 256 = 4 waves; wave w owns ctx rows m0+w*16..+15, full q=512.
//
// LEDGER: R11 global-B = latency collapse. R14 tr_b16 = wrong elem order. R15 reg
//   double-buffer = scratch spills (WRITE 16->40MB). R12/R16: three staging variants
//   all ~42us -> wall is NOT staging; it's per-op latency serialization (~80 cyc/inst,
//   zero ILP: per-kk serial chain S->exp->pack->shuffle->PV at 2 waves/SIMD).
// R17 (this): batched phases + free double-hidden DMA, same 2 barriers/chunk:
//   [syncA: drains Q(c) DMA + PV(c-1) lgkm reads -> stage V(c) DMA
//    -> S-phase (all 32 MFMA, 8 indep chains) -> E-phase (all exp+pack)
//    -> X-phase (all 32 bpermutes)
//    -> syncB: drains V(c) DMA (hidden under S/E/X) + S qch reads
//    -> PV (32 MFMA, 8 indep chains) + issue Q(c+1) DMA (hidden under PV+syncA)]
//   Hazards: stageQ(c+1) writes qch, S-reads drained at syncB; stageV(c) writes vch,
//   PV(c-1) reads drained at syncA; single-buffered, no counted-vmcnt tricks.
// Max-subtraction dropped (S_max ~16 << 88; -8 centering in maskh; R10-verified).
// __launch_bounds__ min-waves MUST stay 2 (3 => 84-VGPR spill binary, R6/R8).
__global__ __launch_bounds__(256, 2) void k_attn(const float* __restrict__ ctx,
                                                 const short* __restrict__ wsw,
                                                 const float* __restrict__ bias,
                                                 const int* __restrict__ mask,
                                                 const short* __restrict__ ql,
                                                 const short* __restrict__ qlT,
                                                 float* __restrict__ out) {
  const int b = blockIdx.y;
  const int m0 = blockIdx.x * 64;
  const int tid = threadIdx.x;
  const int w = tid >> 6, l = tid & 63, t = l & 15, quad = l >> 4;
  const int g = w >> 1, hf = w & 1;

  __shared__ __align__(16) short uq[16384];  // cst [32][328] (20,992 B) -> qch [128][128]
  __shared__ __align__(16) short uv[16384];  // clt [64][136] (17,408 B) -> vch [128][128]
  __shared__ short maskh[SQ];                // bf16 mask+exp-centering offsets
  short* cst = uq;
  short* qch = uq;
  short* clt = uv;
  short* vch = uv;

  for (int i = tid; i < SQ; i += 256)
    maskh[i] = f2bf(mask[b * SQ + i] ? -8.0f : -1e30f);  // -8 = exp-centering offset

  // ---- phase A: ctx_logits tile [64][128], two 32-row halves ----
  for (int i = 0; i < 2; ++i) {
    const float4* cbase = (const float4*)(ctx + ((size_t)b * SCTX + m0 + i * 32) * EE);
#pragma unroll
    for (int j = 0; j < 10; ++j) {
      int i4 = tid + j * 256;
      if (i4 < 2400) {
        float4 v = cbase[i4];
        int row = i4 / 75, c4 = i4 - row * 75;
        bhalf4 s4; s4[0] = f2bf(v.x); s4[1] = f2bf(v.y); s4[2] = f2bf(v.z); s4[3] = f2bf(v.w);
        *(bhalf4*)(cst + row * CST + c4 * 4) = s4;
      }
    }
    for (int k = tid; k < 320; k += 256) {
      int row = k / 10, c = (k - row * 10) * 2;
      *(int*)&cst[row * CST + 300 + c] = 0;
    }
    __syncthreads();
    const short* arow = cst + (g * 16 + t) * CST;
    f32x4 acc[4] = {};
#pragma unroll
    for (int kk = 0; kk < 10; ++kk) {
      const int k = kk * 32 + quad * 8;
      short8 a = *(const short8*)(arow + k);
      short8 w8[4];
#pragma unroll
      for (int n = 0; n < 4; ++n)
        w8[n] = *(const short8*)(wsw + ((kk * 8 + hf * 4 + n) * 64 + l) * 8);
#pragma unroll
      for (int n = 0; n < 4; ++n) acc[n] = MFMA16(a, w8[n], acc[n]);
    }
#pragma unroll
    for (int n = 0; n < 4; ++n) {
      const int h = (hf * 4 + n) * 16 + t;
      const float bv = bias[h];
#pragma unroll
      for (int r = 0; r < 4; ++r) {
        float v = fmaxf(acc[n][r] + bv, 0.0f);
        clt[(i * 32 + g * 16 + quad * 4 + r) * 136 + h] = f2bf(v);
      }
    }
    __syncthreads();  // clt written; cst free (lgkm drained)
  }

  // A-fragments for this wave's 16 ctx rows (lgkm reads; drained at first syncA)
  short8 af[4];
#pragma unroll
  for (int kk = 0; kk < 4; ++kk)
    af[kk] = *(const short8*)&clt[(w * 16 + t) * 136 + kk * 32 + quad * 8];

  const int srcA = ((quad & 1) * 2) * 16 + t;  // shfl source lanes for P-assembly
  const int srcB = srcA + 16;
  const bool hiq = quad >= 2;                  // dest-quad half selects n2 parity
  const int sx = (t & 7) << 3;                 // read-side XOR (shorts)
  const int rl = l >> 4;                       // DMA: lane's row-within-call
  const int cb = (l & 15) * 16;                // DMA: lane's linear dest col-byte

  // DMA stagers: 8 calls/wave each; dest wave-uniform, source pre-swizzled.
  auto stageQ = [&](int c) {
#pragma unroll
    for (int s = 0; s < 8; ++s) {
      const int row = w * 32 + s * 4 + rl;
      const int sw = cb ^ ((row & 7) << 4);
      gload16((const char*)(ql + ((size_t)b * SQ + c * 128 + row) * HH) + sw,
              qch + (w * 32 + s * 4) * 128);
    }
  };
  auto stageV = [&](int c) {
#pragma unroll
    for (int s = 0; s < 8; ++s) {
      const int row = w * 32 + s * 4 + rl;
      const int sw = cb ^ ((row & 7) << 4);
      gload16((const char*)(qlT + ((size_t)b * HH + row) * SQ + c * 128) + sw,
              vch + (w * 32 + s * 4) * 128);
    }
  };

  stageQ(0);  // flies under the epilogue of phase A + syncA

  f32x4 o[8] = {};
  float rtot = 0.0f;
  for (int c = 0; c < 4; ++c) {
    __syncthreads();  // syncA: Q(c) DMA drained; af/PV(c-1) lgkm reads drained
    stageV(c);        // V(c) DMA flies under S/E/X phases

    // ---- S phase: all 32 MFMAs, 8 independent accumulator chains ----
    f32x4 sv[8] = {};
#pragma unroll
    for (int kk = 0; kk < 4; ++kk) {
      const short* qrE = qch + ((kk * 2) * 16 + t) * 128;
      const short* qrO = qrE + 16 * 128;
#pragma unroll
      for (int kx = 0; kx < 4; ++kx) {
        const int co = (kx * 32 + quad * 8) ^ sx;
        sv[kk * 2]     = MFMA16(*(const short8*)(qrE + co), af[kx], sv[kk * 2]);
        sv[kk * 2 + 1] = MFMA16(*(const short8*)(qrO + co), af[kx], sv[kk * 2 + 1]);
      }
    }
    // ---- E phase: all exp + pack -> pk[16] ----
    unsigned pk[16];
#pragma unroll
    for (int kk = 0; kk < 4; ++kk) {
      bhalf4 mbE = *(const bhalf4*)&maskh[c * 128 + (kk * 2) * 16 + quad * 4];
      bhalf4 mbO = *(const bhalf4*)&maskh[c * 128 + (kk * 2 + 1) * 16 + quad * 4];
      float pE[4], pO[4];
#pragma unroll
      for (int r = 0; r < 4; ++r) {
        pE[r] = exp2f((sv[kk * 2][r] + bf2f(mbE[r])) * LOG2E);
        pO[r] = exp2f((sv[kk * 2 + 1][r] + bf2f(mbO[r])) * LOG2E);
        rtot += pE[r] + pO[r];
      }
      pk[kk * 4 + 0] = pack2(pE[0], pE[1]);
      pk[kk * 4 + 1] = pack2(pE[2], pE[3]);
      pk[kk * 4 + 2] = pack2(pO[0], pO[1]);
      pk[kk * 4 + 3] = pack2(pO[2], pO[3]);
    }
    // ---- X phase: all 32 bpermutes (fully independent) ----
    unsigned sA[16], sB[16];
#pragma unroll
    for (int i = 0; i < 16; ++i) {
      sA[i] = (unsigned)__shfl((int)pk[i], srcA);
      sB[i] = (unsigned)__shfl((int)pk[i], srcB);
    }

    __syncthreads();  // syncB: V(c) DMA drained (hidden under S/E/X); S qch reads drained

    if (c < 3) stageQ(c + 1);  // Q(c+1) DMA flies under PV + next syncA

    // ---- PV phase: 32 MFMAs, 8 independent accumulator chains ----
#pragma unroll
    for (int kk = 0; kk < 4; ++kk) {
      u32x4 av;
      av[0] = hiq ? sA[kk * 4 + 2] : sA[kk * 4 + 0];  // j=0,1
      av[1] = hiq ? sA[kk * 4 + 3] : sA[kk * 4 + 1];  // j=2,3
      av[2] = hiq ? sB[kk * 4 + 2] : sB[kk * 4 + 0];  // j=4,5
      av[3] = hiq ? sB[kk * 4 + 3] : sB[kk * 4 + 1];  // j=6,7
      short8 pa = __builtin_bit_cast(short8, av);
      const int co = (kk * 32 + quad * 8) ^ sx;
#pragma unroll
      for (int n = 0; n < 8; ++n) {
        short8 v8 = *(const short8*)&vch[(n * 16 + t) * 128 + co];
        o[n] = MFMA16(pa, v8, o[n]);
      }
    }
  }

  // ---- epilogue ----
  rtot += __shfl_xor(rtot, 16);
  rtot += __shfl_xor(rtot, 32);  // lane x now holds full denom for ctx row (x&15)
  f32x4 rinv;
#pragma unroll
  for (int r = 0; r < 4; ++r) rinv[r] = 1.0f / __shfl(rtot, quad * 4 + r);
  float* obase = out + ((size_t)b * SCTX + m0 + w * 16) * HH;
#pragma unroll
  for (int n = 0; n < 8; ++n)
#pragma unroll
    for (int r = 0; r < 4; ++r)
      obase[(quad * 4 + r) * HH + n * 16 + t] = o[n][r] * rinv[r];
}

extern "C" void kernel_launch(void* const* d_in, const int* in_sizes, int n_in,
                              void* d_out, int out_size, void* d_ws, size_t ws_size,
                              hipStream_t stream) {
  const float* ctx  = (const float*)d_in[0];
  const float* qst  = (const float*)d_in[1];
  const int*   mask = (const int*)d_in[2];
  const float* W    = (const float*)d_in[3];
  const float* bias = (const float*)d_in[4];
  float* out = (float*)d_out;

  // ws: wsw 80 KiB | ql 1 MiB | qlT 1 MiB
  short* wsw  = (short*)d_ws;
  short* ql   = (short*)((char*)d_ws + 81920);
  short* qlT  = ql + (size_t)BB * SQ * HH;

  k_wpad<<<dim3(HH), dim3(EP), 0, stream>>>(W, wsw);
  k_qlog<<<dim3(SQ / 32, BB), dim3(256), 0, stream>>>(qst, wsw, bias, ql, qlT);
  k_attn<<<dim3(SCTX / 64, BB), dim3(256), 0, stream>>>(ctx, wsw, bias, mask, ql, qlT, out);
}